// Round 8
// baseline (319.938 us; speedup 1.0000x reference)
//
#include <hip/hip_runtime.h>
#include <hip/hip_bf16.h>

// ---------------------------------------------------------------------------
// DeformableSpatialEncoder on MI355X (gfx950)
//
// Linearity-collapsed pipeline (R5) + dispatch-collapse (R8).
// Model (from R3..R7 deltas): ~150 µs fixed harness overhead; small
// serialized GEMM dispatches (wfuse: 42 blocks, ~29 µs) dominate the
// controllable time -> fold ALL weight-fusion GEMMs into stage as
// independent VALU-f32 blocks reading raw inputs (no intra-launch deps).
//
//   core_m[n] = ( Wfv_m · s_{n,m} + S_{n,m} · bfused_m ) / 196
//   s_{n,m}   = Σ_tok coeff_m[n][tok] · A[n,tok,:]
//   coeff     = scattered softmax×bilinear weights (off/aw cols only)
//   final     = core @ Wpp^T + bpp,  Wpp = proj_w@outp_w (mean commuted)
//
// 4 dispatches:
//   1. stage:   [0,306)   Wfused bf16 [896,768] = Wcat@Wemb   (VALU f32)
//               [306,594) Wpp f32 [768,768]     = proj@outp   (VALU f32)
//               [594,661) bfused / bpp dots, zero-fill Wfused rows 816+
//               [661,10069) im2col x -> A bf16 [12544,768]
//   2. gemm_oa: OA f32 [12544,64] = A @ Wfused[768:896]^T + bfused[768:]
//   3. percore: grid (64,4) — coeff scatter -> s = coeff@A_n -> core
//   4. final:   out = core @ Wpp^T + bpp       grid (64,3)
// ---------------------------------------------------------------------------

using bf16 = __bf16;
typedef bf16  bf16x8 __attribute__((ext_vector_type(8)));
typedef float f32x4  __attribute__((ext_vector_type(4)));

#define N_IMG   64
#define LQ      196
#define DM      768
#define NH      4
#define DH      192
#define M_ROWS  (N_IMG * LQ)        // 12544

// ---- workspace layout (bytes) ----
#define OFF_A      ((size_t)0)                     // 12544*768*2 = 19267584
#define OFF_WFUSE  (OFF_A     + 19267584)          // 896*768*2   = 1376256
#define OFF_BFUSE  (OFF_WFUSE + 1376256)           // 4096
#define OFF_WPP    (OFF_BFUSE + 4096)              // 768*768*4   = 2359296
#define OFF_BPP    (OFF_WPP   + 2359296)           // 4096
#define OFF_OA     (OFF_BPP   + 4096)              // 12544*64*4  = 3211264
#define OFF_CORE   (OFF_OA    + 3211264)           // 196608

__device__ __forceinline__ void gload_lds16(const bf16* g, bf16* l) {
#if __has_builtin(__builtin_amdgcn_global_load_lds)
  __builtin_amdgcn_global_load_lds(
      (const __attribute__((address_space(1))) void*)g,
      (__attribute__((address_space(3))) void*)l, 16, 0, 0);
#else
  *(bf16x8*)l = *(const bf16x8*)g;
#endif
}

// ---------------------------------------------------------------------------
// stage: all independent blocks, raw-input reads only.
// VALU GEMM tile: 16 rows x 128 cols, thread=(kl 0..127, rh 0..1) owns 8 rows.
// Weight loads wave-uniform (scalar), embed/outp reads coalesced.
// ---------------------------------------------------------------------------
__global__ void stage_kernel(const float* __restrict__ x,
                             const float* __restrict__ embed_w,
                             const float* __restrict__ embed_b,
                             const float* __restrict__ value_w,
                             const float* __restrict__ off_w,
                             const float* __restrict__ aw_w,
                             const float* __restrict__ value_b,
                             const float* __restrict__ off_b,
                             const float* __restrict__ aw_b,
                             const float* __restrict__ outp_w,
                             const float* __restrict__ outp_b,
                             const float* __restrict__ proj_w,
                             const float* __restrict__ proj_b,
                             bf16* __restrict__ A,
                             bf16* __restrict__ Wfused,
                             float* __restrict__ bfused,
                             float* __restrict__ Wpp,
                             float* __restrict__ bpp) {
  const int bid = blockIdx.x;
  const int tid = threadIdx.x;

  if (bid < 306) {           // ---- Wfused = Wcat @ Wemb (f32 VALU) ----
    const int rt = bid / 6, kt = bid - rt * 6;     // rt 0..50
    const int r0 = rt * 16;                        // 0..800
    const int k  = kt * 128 + (tid & 127);
    const int rh = tid >> 7;                       // 0..1 (wave-uniform)
    const float* src;                              // 8 rows starting here
    if (rt < 48)      src = value_w + (size_t)(r0 + rh * 8) * DM;
    else if (rt < 50) src = off_w  + (size_t)(r0 - 768 + rh * 8) * DM;
    else              src = aw_w   + (size_t)(r0 - 800 + rh * 8) * DM;
    float acc[8];
#pragma unroll
    for (int i = 0; i < 8; ++i) acc[i] = 0.f;
#pragma unroll 4
    for (int j = 0; j < DM; ++j) {
      const float e = embed_w[(size_t)j * DM + k];
#pragma unroll
      for (int i = 0; i < 8; ++i) acc[i] += src[(size_t)i * DM + j] * e;
    }
#pragma unroll
    for (int i = 0; i < 8; ++i)
      Wfused[(size_t)(r0 + rh * 8 + i) * DM + k] = (bf16)acc[i];
    return;
  }
  if (bid < 594) {           // ---- Wpp = proj_w @ outp_w (f32 VALU) ----
    const int b  = bid - 306;
    const int rt = b / 6, kt = b - rt * 6;         // rt 0..47
    const int r0 = rt * 16;
    const int k  = kt * 128 + (tid & 127);
    const int rh = tid >> 7;
    const float* src = proj_w + (size_t)(r0 + rh * 8) * DM;
    float acc[8];
#pragma unroll
    for (int i = 0; i < 8; ++i) acc[i] = 0.f;
#pragma unroll 4
    for (int j = 0; j < DM; ++j) {
      const float e = outp_w[(size_t)j * DM + k];
#pragma unroll
      for (int i = 0; i < 8; ++i) acc[i] += src[(size_t)i * DM + j] * e;
    }
#pragma unroll
    for (int i = 0; i < 8; ++i)
      Wpp[(size_t)(r0 + rh * 8 + i) * DM + k] = acc[i];
    return;
  }
  if (bid < 661) {           // ---- misc: bfused, bpp, zero-fill ----
    const int mb = bid - 594;
    if (mb < 28) {           // bfused[896] = Wcat@embed_b + orig bias
      const int r  = mb * 32 + (tid >> 3);
      const int t8 = tid & 7;
      const float* src = nullptr;
      float badd = 0.f;
      if (r < 768)      { src = value_w + (size_t)r * DM;        badd = value_b[r]; }
      else if (r < 800) { src = off_w  + (size_t)(r - 768) * DM; badd = off_b[r - 768]; }
      else if (r < 816) { src = aw_w   + (size_t)(r - 800) * DM; badd = aw_b[r - 800]; }
      float s = 0.f;
      if (src) for (int j = t8; j < DM; j += 8) s += src[j] * embed_b[j];
#pragma unroll
      for (int o = 4; o >= 1; o >>= 1) s += __shfl_down(s, o, 8);
      if (t8 == 0) bfused[r] = (src ? s + badd : 0.f);
    } else if (mb < 52) {    // bpp[768] = proj_w@outp_b + proj_b
      const int r  = (mb - 28) * 32 + (tid >> 3);
      const int t8 = tid & 7;
      const float* src = proj_w + (size_t)r * DM;
      float s = 0.f;
      for (int j = t8; j < DM; j += 8) s += src[j] * outp_b[j];
#pragma unroll
      for (int o = 4; o >= 1; o >>= 1) s += __shfl_down(s, o, 8);
      if (t8 == 0) bpp[r] = s + proj_b[r];
    } else {                 // zero Wfused rows 816..895 (80*768 elems)
      const int idx = (mb - 52) * 4096 + tid * 16;
      bf16* dst = Wfused + (size_t)816 * DM + idx;
#pragma unroll
      for (int i = 0; i < 16; ++i) dst[i] = (bf16)0.f;
    }
    return;
  }
  // ---- im2col: A[row][k], row=n*196+h*14+w, k=c*256+p*16+q ----
  const int t   = (bid - 661) * 256 + tid;         // < 12544*192 exactly
  const int row = t / 192;
  const int j   = t - row * 192;
  const int k   = j * 4;
  const int c   = k >> 8;
  const int r   = k & 255;
  const int p   = r >> 4;
  const int q   = r & 15;
  const int n   = row / 196;
  const int lq  = row - n * 196;
  const int h   = lq / 14;
  const int w   = lq - h * 14;
  const float4 v = *(const float4*)(x +
      ((((size_t)n * 3 + c) * 224) + h * 16 + p) * 224 + w * 16 + q);
  bf16* dst = A + (size_t)row * DM + k;
  dst[0] = (bf16)v.x; dst[1] = (bf16)v.y; dst[2] = (bf16)v.z; dst[3] = (bf16)v.w;
}

// ---------------------------------------------------------------------------
// gemm_oa: OA[M,64] f32 = A[M,768] @ B128[128,768]^T + bias[128], cols<64 kept.
// B128 = Wfused rows 768..895 (816+ zero). grid(98), 256 thr, MFMA.
// ---------------------------------------------------------------------------
__global__ void gemm_oa(const bf16* __restrict__ A, const bf16* __restrict__ B,
                        const float* __restrict__ bias, float* __restrict__ OA,
                        int K) {
  __shared__ bf16 As[128 * 64];
  __shared__ bf16 Bs[128 * 64];

  const int tid  = threadIdx.x;
  const int wave = tid >> 6;
  const int lane = tid & 63;
  const int mBase = blockIdx.x * 128;
  const int wm = wave & 1;
  const int wn = wave >> 1;
  const int quad = lane >> 4;
  const int r16  = lane & 15;

  const f32x4 zero = {0.f, 0.f, 0.f, 0.f};
  f32x4 acc[4][4];
#pragma unroll
  for (int mi = 0; mi < 4; ++mi)
#pragma unroll
    for (int ni = 0; ni < 4; ++ni) acc[mi][ni] = zero;

  const int srow = wave * 32 + (lane >> 3);
  const int scol = (lane & 7) * 8;
  const bf16* Ag = A + (size_t)(mBase + srow) * K + scol;
  const bf16* Bg = B + (size_t)srow * K + scol;
  bf16* Al = As + srow * 64 + scol;
  bf16* Bl = Bs + srow * 64 + scol;

  for (int kt = 0; kt < K; kt += 64) {
#pragma unroll
    for (int i = 0; i < 4; ++i) {
      gload_lds16(Ag + (size_t)(i * 8) * K + kt, Al + i * 8 * 64);
      gload_lds16(Bg + (size_t)(i * 8) * K + kt, Bl + i * 8 * 64);
    }
    __syncthreads();
#pragma unroll
    for (int kk = 0; kk < 64; kk += 32) {
      bf16x8 af[4], bfr[4];
#pragma unroll
      for (int mi = 0; mi < 4; ++mi)
        af[mi] = *(const bf16x8*)&As[(wm * 64 + mi * 16 + r16) * 64 + kk + quad * 8];
#pragma unroll
      for (int ni = 0; ni < 4; ++ni)
        bfr[ni] = *(const bf16x8*)&Bs[(wn * 64 + ni * 16 + r16) * 64 + kk + quad * 8];
#pragma unroll
      for (int mi = 0; mi < 4; ++mi)
#pragma unroll
        for (int ni = 0; ni < 4; ++ni)
          acc[mi][ni] = __builtin_amdgcn_mfma_f32_16x16x32_bf16(
              af[mi], bfr[ni], acc[mi][ni], 0, 0, 0);
    }
    __syncthreads();
  }

#pragma unroll
  for (int ni = 0; ni < 4; ++ni) {
    const int col = wn * 64 + ni * 16 + r16;
    if (col >= 64) continue;
    const float bv = bias[col];
#pragma unroll
    for (int mi = 0; mi < 4; ++mi) {
      const int row0 = mBase + wm * 64 + mi * 16 + quad * 4;
#pragma unroll
      for (int rr = 0; rr < 4; ++rr) {
        OA[(size_t)(row0 + rr) * 64 + col] = acc[mi][ni][rr] + bv;
      }
    }
  }
}

// ---------------------------------------------------------------------------
// percore: grid (64, 4) = (image n, head m), block 256.
// A) scatter softmax*bilinear weights into coeff[196] (LDS atomics), S=Σcoeff
// B) s[768] = Σ_tok coeff[tok]*A[n,tok,:] — wave q owns 49 tokens, 12 acc ILP
// C) core[n][m*192+d] = (Wfv[m*192+d]·s + S*bfused[m*192+d]) / 196
// ---------------------------------------------------------------------------
__global__ void percore_kernel(const bf16* __restrict__ A,
                               const float* __restrict__ OA,
                               const bf16* __restrict__ Wfused,
                               const float* __restrict__ bfused,
                               float* __restrict__ core) {
  __shared__ float sC[LQ];
  __shared__ float sP[4][DM];
  __shared__ float sS[DM];
  __shared__ float sSum;

  const int n = blockIdx.x;
  const int m = blockIdx.y;
  const int tid = threadIdx.x;

  if (tid < LQ) sC[tid] = 0.f;
  if (tid == 0) sSum = 0.f;
  __syncthreads();

  const float* oa = OA + (size_t)n * LQ * 64;
  for (int t = tid; t < LQ * 4; t += 256) {
    const int lq = t >> 2, p = t & 3;
    const float* row = oa + (size_t)lq * 64;
    const float l0 = row[32 + m * 4 + 0];
    const float l1 = row[32 + m * 4 + 1];
    const float l2 = row[32 + m * 4 + 2];
    const float l3 = row[32 + m * 4 + 3];
    const float mx = fmaxf(fmaxf(l0, l1), fmaxf(l2, l3));
    const float e0 = __expf(l0 - mx), e1 = __expf(l1 - mx);
    const float e2 = __expf(l2 - mx), e3 = __expf(l3 - mx);
    const float inv = 1.f / (e0 + e1 + e2 + e3);
    const float ep[4] = {e0, e1, e2, e3};
    const float ew = ep[p] * inv;

    const int h = lq / 14, w = lq - (lq / 14) * 14;
    const float px = (float)w * (14.f / 13.f) - 0.5f + row[(m * 4 + p) * 2 + 0];
    const float py = (float)h * (14.f / 13.f) - 0.5f + row[(m * 4 + p) * 2 + 1];
    const float fx = floorf(px), fy = floorf(py);
    const int x0 = (int)fx, y0 = (int)fy;
    const float wx1 = px - fx, wy1 = py - fy;
    const float wx0 = 1.f - wx1, wy0 = 1.f - wy1;

    const bool vx0 = (x0 >= 0) & (x0 < 14);
    const bool vx1 = (x0 >= -1) & (x0 < 13);
    const bool vy0 = (y0 >= 0) & (y0 < 14);
    const bool vy1 = (y0 >= -1) & (y0 < 13);
    const int cx0 = min(max(x0, 0), 13),      cx1 = min(max(x0 + 1, 0), 13);
    const int cy0 = min(max(y0, 0), 13) * 14, cy1 = min(max(y0 + 1, 0), 13) * 14;

    atomicAdd(&sC[cy0 + cx0], (vx0 & vy0) ? ew * wx0 * wy0 : 0.f);
    atomicAdd(&sC[cy0 + cx1], (vx1 & vy0) ? ew * wx1 * wy0 : 0.f);
    atomicAdd(&sC[cy1 + cx0], (vx0 & vy1) ? ew * wx0 * wy1 : 0.f);
    atomicAdd(&sC[cy1 + cx1], (vx1 & vy1) ? ew * wx1 * wy1 : 0.f);
  }
  __syncthreads();
  if (tid < LQ) atomicAdd(&sSum, sC[tid]);

  {
    const int q = tid >> 6, lane = tid & 63;
    const bf16* an = A + (size_t)n * LQ * DM;
    float acc[12];
#pragma unroll
    for (int j = 0; j < 12; ++j) acc[j] = 0.f;
    const int t0 = q * 49;
    for (int tok = t0; tok < t0 + 49; ++tok) {
      const float cf = sC[tok];
      const bf16* ar = an + (size_t)tok * DM + lane;
#pragma unroll
      for (int j = 0; j < 12; ++j) acc[j] += cf * (float)ar[64 * j];
    }
#pragma unroll
    for (int j = 0; j < 12; ++j) sP[q][lane + 64 * j] = acc[j];
  }
  __syncthreads();
  for (int c = tid; c < DM; c += 256)
    sS[c] = sP[0][c] + sP[1][c] + sP[2][c] + sP[3][c];
  __syncthreads();

  if (tid < DH) {
    const int ch = m * DH + tid;
    const bf16* wr = Wfused + (size_t)ch * DM;
    float acc = 0.f;
    for (int k = 0; k < DM; k += 8) {
      const bf16x8 wv = *(const bf16x8*)(wr + k);
#pragma unroll
      for (int j = 0; j < 8; ++j) acc += (float)wv[j] * sS[k + j];
    }
    core[(size_t)n * DM + ch] = (acc + sSum * bfused[ch]) * (1.f / 196.f);
  }
}

// ---------------------------------------------------------------------------
// final_linear: out[n][d] = core[n]·Wpp[d] + bpp[d].  grid (64,3), block 256.
// ---------------------------------------------------------------------------
__global__ void final_linear(const float* __restrict__ in,
                             const float* __restrict__ W,
                             const float* __restrict__ b,
                             float* __restrict__ out) {
  const int n = blockIdx.x;
  const int d = blockIdx.y * 256 + threadIdx.x;
  const float4* a4 = (const float4*)(in + (size_t)n * DM);
  const float4* w4 = (const float4*)(W + (size_t)d * DM);
  float acc = 0.f;
#pragma unroll 4
  for (int k = 0; k < DM / 4; ++k) {
    float4 a = a4[k], w = w4[k];
    acc += a.x * w.x + a.y * w.y + a.z * w.z + a.w * w.w;
  }
  out[(size_t)n * DM + d] = acc + b[d];
}

// ---------------------------------------------------------------------------
extern "C" void kernel_launch(void* const* d_in, const int* in_sizes, int n_in,
                              void* d_out, int out_size, void* d_ws, size_t ws_size,
                              hipStream_t stream) {
  const float* x       = (const float*)d_in[0];
  const float* embed_w = (const float*)d_in[1];
  const float* embed_b = (const float*)d_in[2];
  const float* value_w = (const float*)d_in[3];
  const float* value_b = (const float*)d_in[4];
  const float* off_w   = (const float*)d_in[5];
  const float* off_b   = (const float*)d_in[6];
  const float* aw_w    = (const float*)d_in[7];
  const float* aw_b    = (const float*)d_in[8];
  const float* outp_w  = (const float*)d_in[9];
  const float* outp_b  = (const float*)d_in[10];
  const float* proj_w  = (const float*)d_in[11];
  const float* proj_b  = (const float*)d_in[12];
  float* out = (float*)d_out;

  char* ws = (char*)d_ws;
  bf16*  A      = (bf16*)(ws + OFF_A);
  bf16*  Wfused = (bf16*)(ws + OFF_WFUSE);
  float* bfused = (float*)(ws + OFF_BFUSE);
  float* Wpp    = (float*)(ws + OFF_WPP);
  float* bpp    = (float*)(ws + OFF_BPP);
  float* OA     = (float*)(ws + OFF_OA);
  float* core   = (float*)(ws + OFF_CORE);

  stage_kernel<<<dim3(10069), dim3(256), 0, stream>>>(
      x, embed_w, embed_b, value_w, off_w, aw_w, value_b, off_b, aw_b,
      outp_w, outp_b, proj_w, proj_b, A, Wfused, bfused, Wpp, bpp);

  gemm_oa<<<dim3(M_ROWS / 128), dim3(256), 0, stream>>>(
      A, Wfused + (size_t)768 * DM, bfused + 768, OA, DM);

  percore_kernel<<<dim3(N_IMG, NH), dim3(256), 0, stream>>>(
      A, OA, Wfused, bfused, core);

  final_linear<<<dim3(64, 3), dim3(256), 0, stream>>>(core, Wpp, bpp, out);
}

// Round 9
// 318.963 us; speedup vs baseline: 1.0031x; 1.0031x over previous
//
#include <hip/hip_runtime.h>
#include <hip/hip_bf16.h>

// ---------------------------------------------------------------------------
// DeformableSpatialEncoder on MI355X (gfx950)
//
// Linearity-collapsed pipeline (R5) + MFMA-in-stage weight fusion (R9).
//   core_m[n] = ( Wfv_m · s_{n,m} + S_{n,m} · bfused_m ) / 196
//   s_{n,m}   = Σ_tok coeff_m[n][tok] · A[n,tok,:]
//   coeff     = scattered softmax×bilinear weights (off/aw cols only)
//
// R8 lesson (counters): folding weight fusion as serial VALU loops made
// stage 164 µs (latency-bound 768-deep chains). R9 folds it as MFMA tile
// blocks with IN-REGISTER f32->bf16 cast (no pre-cast dependency), hidden
// under im2col's 9408 HBM-bound blocks.
//
// 5 dispatches:
//   1. stage:   [0,42)    Wfused bf16 [896,768] = Wcat@Wemb  (MFMA, cast-in)
//               [42,70)   bfused[896] = Wcat@embed_b + bias  (8-thr dots)
//               [70,9478) im2col x -> A bf16 [12544,768]
//   2. gemm_oa: OA f32 [12544,64] = A @ Wfused[768:896]^T + bfused[768:]
//   3. percore: grid (64,4) — coeff scatter -> s = coeff@A_n -> core
//   4. lin1:    pooled = core @ outp_w^T + outp_b    grid (64,3)
//   5. lin2:    out = pooled @ proj_w^T + proj_b     grid (64,3)
// ---------------------------------------------------------------------------

using bf16 = __bf16;
typedef bf16  bf16x4 __attribute__((ext_vector_type(4)));
typedef bf16  bf16x8 __attribute__((ext_vector_type(8)));
typedef float f32x4  __attribute__((ext_vector_type(4)));

#define N_IMG   64
#define LQ      196
#define DM      768
#define NH      4
#define DH      192
#define M_ROWS  (N_IMG * LQ)        // 12544

// ---- workspace layout (bytes) ----
#define OFF_A      ((size_t)0)                     // 12544*768*2 = 19267584
#define OFF_WFUSE  (OFF_A     + 19267584)          // 896*768*2   = 1376256
#define OFF_BFUSE  (OFF_WFUSE + 1376256)           // 4096
#define OFF_OA     (OFF_BFUSE + 4096)              // 12544*64*4  = 3211264
#define OFF_CORE   (OFF_OA    + 3211264)           // 196608
#define OFF_POOL   (OFF_CORE  + 196608)            // 196608

__device__ __forceinline__ void gload_lds16(const bf16* g, bf16* l) {
#if __has_builtin(__builtin_amdgcn_global_load_lds)
  __builtin_amdgcn_global_load_lds(
      (const __attribute__((address_space(1))) void*)g,
      (__attribute__((address_space(3))) void*)l, 16, 0, 0);
#else
  *(bf16x8*)l = *(const bf16x8*)g;
#endif
}

// ---------------------------------------------------------------------------
// stage: one launch, three block classes (all independent, raw-input reads):
//  [0,42)    wfuse-MFMA: Wfused tile 128x128, K=768. Stages raw f32 weights,
//            casts in-register to bf16 LDS tiles, standard MFMA loop.
//            Rows >=816 read as zero -> epilogue writes zeros (no memset).
//  [42,70)   bfused dots (8 threads per output).
//  [70,9478) im2col (coalesced reads+writes).
// ---------------------------------------------------------------------------
__global__ void stage_kernel(const float* __restrict__ x,
                             const float* __restrict__ embed_w,
                             const float* __restrict__ embed_b,
                             const float* __restrict__ value_w,
                             const float* __restrict__ off_w,
                             const float* __restrict__ aw_w,
                             const float* __restrict__ value_b,
                             const float* __restrict__ off_b,
                             const float* __restrict__ aw_b,
                             bf16* __restrict__ A,
                             bf16* __restrict__ Wfused,
                             float* __restrict__ bfused) {
  __shared__ bf16 As[128 * 64];
  __shared__ bf16 Bs[128 * 64];

  const int bid = blockIdx.x;
  const int tid = threadIdx.x;

  if (bid < 42) {            // ---- Wfused = Wcat @ Wemb (MFMA, cast-in) ----
    const int rt = bid / 6, kt = bid - rt * 6;
    const int r0 = rt * 128, k0 = kt * 128;
    const int wave = tid >> 6;
    const int lane = tid & 63;
    const int wm = wave & 1, wn = wave >> 1;
    const int quad = lane >> 4, r16 = lane & 15;

    const f32x4 zero = {0.f, 0.f, 0.f, 0.f};
    f32x4 acc[4][4];
#pragma unroll
    for (int mi = 0; mi < 4; ++mi)
#pragma unroll
      for (int ni = 0; ni < 4; ++ni) acc[mi][ni] = zero;

    for (int jt = 0; jt < DM; jt += 64) {
      // A tile: composite Wcat rows r0..r0+128, cols jt..jt+64 (f32->bf16)
#pragma unroll
      for (int p = 0; p < 8; ++p) {
        const int i   = p * 256 + tid;       // 0..2047
        const int row = i >> 4;
        const int c4  = (i & 15) * 4;
        const int r   = r0 + row;
        float4 v = {0.f, 0.f, 0.f, 0.f};
        if (r < 768)      v = *(const float4*)(value_w + (size_t)r * DM + jt + c4);
        else if (r < 800) v = *(const float4*)(off_w + (size_t)(r - 768) * DM + jt + c4);
        else if (r < 816) v = *(const float4*)(aw_w  + (size_t)(r - 800) * DM + jt + c4);
        bf16x4 b4 = {(bf16)v.x, (bf16)v.y, (bf16)v.z, (bf16)v.w};
        *(bf16x4*)&As[row * 64 + c4] = b4;
      }
      // B tile: Bs[kl][j] = Wemb[jt+j][k0+kl]  (lane=j -> conflict-free writes)
#pragma unroll
      for (int p = 0; p < 8; ++p) {
        const int i  = p * 256 + tid;
        const int j  = i & 63;
        const int kq = i >> 6;               // 0..31
        const float4 v = *(const float4*)(embed_w + (size_t)(jt + j) * DM + k0 + kq * 4);
        Bs[(kq * 4 + 0) * 64 + j] = (bf16)v.x;
        Bs[(kq * 4 + 1) * 64 + j] = (bf16)v.y;
        Bs[(kq * 4 + 2) * 64 + j] = (bf16)v.z;
        Bs[(kq * 4 + 3) * 64 + j] = (bf16)v.w;
      }
      __syncthreads();
#pragma unroll
      for (int kk = 0; kk < 64; kk += 32) {
        bf16x8 af[4], bfr[4];
#pragma unroll
        for (int mi = 0; mi < 4; ++mi)
          af[mi] = *(const bf16x8*)&As[(wm * 64 + mi * 16 + r16) * 64 + kk + quad * 8];
#pragma unroll
        for (int ni = 0; ni < 4; ++ni)
          bfr[ni] = *(const bf16x8*)&Bs[(wn * 64 + ni * 16 + r16) * 64 + kk + quad * 8];
#pragma unroll
        for (int mi = 0; mi < 4; ++mi)
#pragma unroll
          for (int ni = 0; ni < 4; ++ni)
            acc[mi][ni] = __builtin_amdgcn_mfma_f32_16x16x32_bf16(
                af[mi], bfr[ni], acc[mi][ni], 0, 0, 0);
      }
      __syncthreads();
    }
    // epilogue: C row = quad*4+reg (M), col = lane&15 (N)
#pragma unroll
    for (int ni = 0; ni < 4; ++ni) {
      const int col = k0 + wn * 64 + ni * 16 + r16;
#pragma unroll
      for (int mi = 0; mi < 4; ++mi) {
        const int row0 = r0 + wm * 64 + mi * 16 + quad * 4;
#pragma unroll
        for (int rr = 0; rr < 4; ++rr)
          Wfused[(size_t)(row0 + rr) * DM + col] = (bf16)acc[mi][ni][rr];
      }
    }
    return;
  }
  if (bid < 70) {            // ---- bfused[896] = Wcat@embed_b + orig bias ----
    const int r  = (bid - 42) * 32 + (tid >> 3);
    const int t8 = tid & 7;
    const float* src = nullptr;
    float badd = 0.f;
    if (r < 768)      { src = value_w + (size_t)r * DM;        badd = value_b[r]; }
    else if (r < 800) { src = off_w  + (size_t)(r - 768) * DM; badd = off_b[r - 768]; }
    else if (r < 816) { src = aw_w   + (size_t)(r - 800) * DM; badd = aw_b[r - 800]; }
    float s = 0.f;
    if (src) for (int j = t8; j < DM; j += 8) s += src[j] * embed_b[j];
#pragma unroll
    for (int o = 4; o >= 1; o >>= 1) s += __shfl_down(s, o, 8);
    if (t8 == 0) bfused[r] = (src ? s + badd : 0.f);
    return;
  }
  // ---- im2col: A[row][k], row=n*196+h*14+w, k=c*256+p*16+q ----
  const int t   = (bid - 70) * 256 + tid;          // < 12544*192 exactly
  const int row = t / 192;
  const int j   = t - row * 192;
  const int k   = j * 4;
  const int c   = k >> 8;
  const int r   = k & 255;
  const int p   = r >> 4;
  const int q   = r & 15;
  const int n   = row / 196;
  const int lq  = row - n * 196;
  const int h   = lq / 14;
  const int w   = lq - h * 14;
  const float4 v = *(const float4*)(x +
      ((((size_t)n * 3 + c) * 224) + h * 16 + p) * 224 + w * 16 + q);
  bf16* dst = A + (size_t)row * DM + k;
  dst[0] = (bf16)v.x; dst[1] = (bf16)v.y; dst[2] = (bf16)v.z; dst[3] = (bf16)v.w;
}

// ---------------------------------------------------------------------------
// gemm_oa: OA[M,64] f32 = A[M,768] @ B128[128,768]^T + bias[128], cols<64 kept.
// B128 = Wfused rows 768..895 (816+ zero). grid(98), 256 thr, MFMA.
// ---------------------------------------------------------------------------
__global__ void gemm_oa(const bf16* __restrict__ A, const bf16* __restrict__ B,
                        const float* __restrict__ bias, float* __restrict__ OA,
                        int K) {
  __shared__ bf16 As[128 * 64];
  __shared__ bf16 Bs[128 * 64];

  const int tid  = threadIdx.x;
  const int wave = tid >> 6;
  const int lane = tid & 63;
  const int mBase = blockIdx.x * 128;
  const int wm = wave & 1;
  const int wn = wave >> 1;
  const int quad = lane >> 4;
  const int r16  = lane & 15;

  const f32x4 zero = {0.f, 0.f, 0.f, 0.f};
  f32x4 acc[4][4];
#pragma unroll
  for (int mi = 0; mi < 4; ++mi)
#pragma unroll
    for (int ni = 0; ni < 4; ++ni) acc[mi][ni] = zero;

  const int srow = wave * 32 + (lane >> 3);
  const int scol = (lane & 7) * 8;
  const bf16* Ag = A + (size_t)(mBase + srow) * K + scol;
  const bf16* Bg = B + (size_t)srow * K + scol;
  bf16* Al = As + srow * 64 + scol;
  bf16* Bl = Bs + srow * 64 + scol;

  for (int kt = 0; kt < K; kt += 64) {
#pragma unroll
    for (int i = 0; i < 4; ++i) {
      gload_lds16(Ag + (size_t)(i * 8) * K + kt, Al + i * 8 * 64);
      gload_lds16(Bg + (size_t)(i * 8) * K + kt, Bl + i * 8 * 64);
    }
    __syncthreads();
#pragma unroll
    for (int kk = 0; kk < 64; kk += 32) {
      bf16x8 af[4], bfr[4];
#pragma unroll
      for (int mi = 0; mi < 4; ++mi)
        af[mi] = *(const bf16x8*)&As[(wm * 64 + mi * 16 + r16) * 64 + kk + quad * 8];
#pragma unroll
      for (int ni = 0; ni < 4; ++ni)
        bfr[ni] = *(const bf16x8*)&Bs[(wn * 64 + ni * 16 + r16) * 64 + kk + quad * 8];
#pragma unroll
      for (int mi = 0; mi < 4; ++mi)
#pragma unroll
        for (int ni = 0; ni < 4; ++ni)
          acc[mi][ni] = __builtin_amdgcn_mfma_f32_16x16x32_bf16(
              af[mi], bfr[ni], acc[mi][ni], 0, 0, 0);
    }
    __syncthreads();
  }

#pragma unroll
  for (int ni = 0; ni < 4; ++ni) {
    const int col = wn * 64 + ni * 16 + r16;
    if (col >= 64) continue;
    const float bv = bias[col];
#pragma unroll
    for (int mi = 0; mi < 4; ++mi) {
      const int row0 = mBase + wm * 64 + mi * 16 + quad * 4;
#pragma unroll
      for (int rr = 0; rr < 4; ++rr) {
        OA[(size_t)(row0 + rr) * 64 + col] = acc[mi][ni][rr] + bv;
      }
    }
  }
}

// ---------------------------------------------------------------------------
// percore: grid (64, 4) = (image n, head m), block 256.
// A) scatter softmax*bilinear weights into coeff[196] (LDS atomics), S=Σcoeff
// B) s[768] = Σ_tok coeff[tok]*A[n,tok,:] — wave q owns 49 tokens, 12 acc ILP
// C) core[n][m*192+d] = (Wfv[m*192+d]·s + S*bfused[m*192+d]) / 196
// ---------------------------------------------------------------------------
__global__ void percore_kernel(const bf16* __restrict__ A,
                               const float* __restrict__ OA,
                               const bf16* __restrict__ Wfused,
                               const float* __restrict__ bfused,
                               float* __restrict__ core) {
  __shared__ float sC[LQ];
  __shared__ float sP[4][DM];
  __shared__ float sS[DM];
  __shared__ float sSum;

  const int n = blockIdx.x;
  const int m = blockIdx.y;
  const int tid = threadIdx.x;

  if (tid < LQ) sC[tid] = 0.f;
  if (tid == 0) sSum = 0.f;
  __syncthreads();

  const float* oa = OA + (size_t)n * LQ * 64;
  for (int t = tid; t < LQ * 4; t += 256) {
    const int lq = t >> 2, p = t & 3;
    const float* row = oa + (size_t)lq * 64;
    const float l0 = row[32 + m * 4 + 0];
    const float l1 = row[32 + m * 4 + 1];
    const float l2 = row[32 + m * 4 + 2];
    const float l3 = row[32 + m * 4 + 3];
    const float mx = fmaxf(fmaxf(l0, l1), fmaxf(l2, l3));
    const float e0 = __expf(l0 - mx), e1 = __expf(l1 - mx);
    const float e2 = __expf(l2 - mx), e3 = __expf(l3 - mx);
    const float inv = 1.f / (e0 + e1 + e2 + e3);
    const float ep[4] = {e0, e1, e2, e3};
    const float ew = ep[p] * inv;

    const int h = lq / 14, w = lq - (lq / 14) * 14;
    const float px = (float)w * (14.f / 13.f) - 0.5f + row[(m * 4 + p) * 2 + 0];
    const float py = (float)h * (14.f / 13.f) - 0.5f + row[(m * 4 + p) * 2 + 1];
    const float fx = floorf(px), fy = floorf(py);
    const int x0 = (int)fx, y0 = (int)fy;
    const float wx1 = px - fx, wy1 = py - fy;
    const float wx0 = 1.f - wx1, wy0 = 1.f - wy1;

    const bool vx0 = (x0 >= 0) & (x0 < 14);
    const bool vx1 = (x0 >= -1) & (x0 < 13);
    const bool vy0 = (y0 >= 0) & (y0 < 14);
    const bool vy1 = (y0 >= -1) & (y0 < 13);
    const int cx0 = min(max(x0, 0), 13),      cx1 = min(max(x0 + 1, 0), 13);
    const int cy0 = min(max(y0, 0), 13) * 14, cy1 = min(max(y0 + 1, 0), 13) * 14;

    atomicAdd(&sC[cy0 + cx0], (vx0 & vy0) ? ew * wx0 * wy0 : 0.f);
    atomicAdd(&sC[cy0 + cx1], (vx1 & vy0) ? ew * wx1 * wy0 : 0.f);
    atomicAdd(&sC[cy1 + cx0], (vx0 & vy1) ? ew * wx0 * wy1 : 0.f);
    atomicAdd(&sC[cy1 + cx1], (vx1 & vy1) ? ew * wx1 * wy1 : 0.f);
  }
  __syncthreads();
  if (tid < LQ) atomicAdd(&sSum, sC[tid]);

  {
    const int q = tid >> 6, lane = tid & 63;
    const bf16* an = A + (size_t)n * LQ * DM;
    float acc[12];
#pragma unroll
    for (int j = 0; j < 12; ++j) acc[j] = 0.f;
    const int t0 = q * 49;
    for (int tok = t0; tok < t0 + 49; ++tok) {
      const float cf = sC[tok];
      const bf16* ar = an + (size_t)tok * DM + lane;
#pragma unroll
      for (int j = 0; j < 12; ++j) acc[j] += cf * (float)ar[64 * j];
    }
#pragma unroll
    for (int j = 0; j < 12; ++j) sP[q][lane + 64 * j] = acc[j];
  }
  __syncthreads();
  for (int c = tid; c < DM; c += 256)
    sS[c] = sP[0][c] + sP[1][c] + sP[2][c] + sP[3][c];
  __syncthreads();

  if (tid < DH) {
    const int ch = m * DH + tid;
    const bf16* wr = Wfused + (size_t)ch * DM;
    float acc = 0.f;
    for (int k = 0; k < DM; k += 8) {
      const bf16x8 wv = *(const bf16x8*)(wr + k);
#pragma unroll
      for (int j = 0; j < 8; ++j) acc += (float)wv[j] * sS[k + j];
    }
    core[(size_t)n * DM + ch] = (acc + sSum * bfused[ch]) * (1.f / 196.f);
  }
}

// ---------------------------------------------------------------------------
// small_linear: out[n][d] = in[n]·W[d] + b[d].  grid (64,3), block 256.
// ---------------------------------------------------------------------------
__global__ void small_linear(const float* __restrict__ in,
                             const float* __restrict__ W,
                             const float* __restrict__ b,
                             float* __restrict__ out) {
  const int n = blockIdx.x;
  const int d = blockIdx.y * 256 + threadIdx.x;
  const float4* a4 = (const float4*)(in + (size_t)n * DM);
  const float4* w4 = (const float4*)(W + (size_t)d * DM);
  float acc = 0.f;
#pragma unroll 4
  for (int k = 0; k < DM / 4; ++k) {
    float4 a = a4[k], w = w4[k];
    acc += a.x * w.x + a.y * w.y + a.z * w.z + a.w * w.w;
  }
  out[(size_t)n * DM + d] = acc + b[d];
}

// ---------------------------------------------------------------------------
extern "C" void kernel_launch(void* const* d_in, const int* in_sizes, int n_in,
                              void* d_out, int out_size, void* d_ws, size_t ws_size,
                              hipStream_t stream) {
  const float* x       = (const float*)d_in[0];
  const float* embed_w = (const float*)d_in[1];
  const float* embed_b = (const float*)d_in[2];
  const float* value_w = (const float*)d_in[3];
  const float* value_b = (const float*)d_in[4];
  const float* off_w   = (const float*)d_in[5];
  const float* off_b   = (const float*)d_in[6];
  const float* aw_w    = (const float*)d_in[7];
  const float* aw_b    = (const float*)d_in[8];
  const float* outp_w  = (const float*)d_in[9];
  const float* outp_b  = (const float*)d_in[10];
  const float* proj_w  = (const float*)d_in[11];
  const float* proj_b  = (const float*)d_in[12];
  float* out = (float*)d_out;

  char* ws = (char*)d_ws;
  bf16*  A      = (bf16*)(ws + OFF_A);
  bf16*  Wfused = (bf16*)(ws + OFF_WFUSE);
  float* bfused = (float*)(ws + OFF_BFUSE);
  float* OA     = (float*)(ws + OFF_OA);
  float* core   = (float*)(ws + OFF_CORE);
  float* pooled = (float*)(ws + OFF_POOL);

  stage_kernel<<<dim3(9478), dim3(256), 0, stream>>>(
      x, embed_w, embed_b, value_w, off_w, aw_w, value_b, off_b, aw_b,
      A, Wfused, bfused);

  gemm_oa<<<dim3(M_ROWS / 128), dim3(256), 0, stream>>>(
      A, Wfused + (size_t)768 * DM, bfused + 768, OA, DM);

  percore_kernel<<<dim3(N_IMG, NH), dim3(256), 0, stream>>>(
      A, OA, Wfused, bfused, core);

  small_linear<<<dim3(64, 3), dim3(256), 0, stream>>>(core, outp_w, outp_b, pooled);
  small_linear<<<dim3(64, 3), dim3(256), 0, stream>>>(pooled, proj_w, proj_b, out);
}